// Round 6
// baseline (133.236 us; speedup 1.0000x reference)
//
#include <hip/hip_runtime.h>
#include <stdint.h>
#include <float.h>

#define BLK 256
#define IPT 8                 // owner points per thread (8 independent min-chains)
#define OWNERS (BLK * IPT)    // 2048 owners per block
#define SLICE 128             // scanned points per block (2 KB LDS)
#define SUB 64                // subtile granularity for deferred-index recovery

typedef unsigned long long ull;

// Monotone float -> uint transform (preserves <, total order) and inverse.
__device__ __forceinline__ unsigned int ford(float f) {
    int b = __float_as_int(f);
    return (b >= 0) ? ((unsigned)b ^ 0x80000000u) : ~(unsigned)b;
}
__device__ __forceinline__ float ford_inv(unsigned int u) {
    int b = (u & 0x80000000u) ? (int)(u ^ 0x80000000u) : (int)~u;
    return __int_as_float(b);
}
__device__ __forceinline__ float vmin(float a, float b) {
    float d;
    asm("v_min_f32 %0, %1, %2" : "=v"(d) : "v"(a), "v"(b));
    return d;
}

// Phase 1: min VALUE only (3 v_fma + 1 v_min per pair), explicit register
// double-buffer of the LDS reads (load-use distance = 4 points = 128 VALU cyc
// > ~120 cyc LDS latency, so no exposed stall). Per 64-pt subtile, record the
// subtile base on strict improvement (numpy first-occurrence). Merge via u64
// atomicMax of ~(ford(best)<<32 | base)  -- complemented so the init state is
// all-ZEROS (one memset covers mins + accumulator + done-counter).
__global__ __launch_bounds__(BLK) void nn_min_dual(
    const float* __restrict__ p, const float* __restrict__ g,
    ull* __restrict__ rowmin, ull* __restrict__ colmin,
    int rowBlocks, int rowSlices, int colSlices)
{
    __shared__ float4 sb[SLICE];

    const float* A; const float* B; ull* outmin; int id, nSlices;
    if ((int)blockIdx.x < rowBlocks) {
        id = blockIdx.x;             A = p; B = g; outmin = rowmin; nSlices = rowSlices;
    } else {
        id = blockIdx.x - rowBlocks; A = g; B = p; outmin = colmin; nSlices = colSlices;
    }
    const int chunk = id / nSlices;
    const int slice = id - chunk * nSlices;
    const int s0 = slice * SLICE;

    // Stage slice (coords + |B|^2). Explicit fmaf: finalize recomputes the
    // identical expression so bit-exact equality holds.
    if (threadIdx.x < SLICE) {
        int s = s0 + threadIdx.x;
        float bx = B[3 * s], by = B[3 * s + 1], bz = B[3 * s + 2];
        float w = fmaf(bz, bz, fmaf(by, by, bx * bx));
        sb[threadIdx.x] = make_float4(bx, by, bz, w);
    }

    const int o0 = chunk * OWNERS + threadIdx.x;
    float ax[IPT], ay[IPT], az[IPT], best[IPT];
    int base[IPT];
#pragma unroll
    for (int r = 0; r < IPT; ++r) {
        int o = o0 + r * BLK;
        ax[r] = -2.0f * A[3 * o];
        ay[r] = -2.0f * A[3 * o + 1];
        az[r] = -2.0f * A[3 * o + 2];
        best[r] = FLT_MAX;
        base[r] = s0;
    }
    __syncthreads();

    for (int st = 0; st < SLICE; st += SUB) {
        float prev[IPT];
#pragma unroll
        for (int r = 0; r < IPT; ++r) prev[r] = best[r];

        // double-buffered scan of the subtile, 4 points per stage
        float4 p0 = sb[st], p1 = sb[st + 1], p2 = sb[st + 2], p3 = sb[st + 3];
#pragma unroll 2
        for (int k = st; k < st + SUB; k += 4) {
            int kn = min(k + 4, SLICE - 4);
            float4 n0 = sb[kn], n1 = sb[kn + 1], n2 = sb[kn + 2], n3 = sb[kn + 3];
#pragma unroll
            for (int r = 0; r < IPT; ++r) {
                float v = fmaf(ax[r], p0.x, fmaf(ay[r], p0.y, fmaf(az[r], p0.z, p0.w)));
                best[r] = vmin(best[r], v);
            }
#pragma unroll
            for (int r = 0; r < IPT; ++r) {
                float v = fmaf(ax[r], p1.x, fmaf(ay[r], p1.y, fmaf(az[r], p1.z, p1.w)));
                best[r] = vmin(best[r], v);
            }
#pragma unroll
            for (int r = 0; r < IPT; ++r) {
                float v = fmaf(ax[r], p2.x, fmaf(ay[r], p2.y, fmaf(az[r], p2.z, p2.w)));
                best[r] = vmin(best[r], v);
            }
#pragma unroll
            for (int r = 0; r < IPT; ++r) {
                float v = fmaf(ax[r], p3.x, fmaf(ay[r], p3.y, fmaf(az[r], p3.z, p3.w)));
                best[r] = vmin(best[r], v);
            }
            p0 = n0; p1 = n1; p2 = n2; p3 = n3;
        }
#pragma unroll
        for (int r = 0; r < IPT; ++r)
            if (best[r] < prev[r]) base[r] = s0 + st;   // strict <: first subtile wins
    }

#pragma unroll
    for (int r = 0; r < IPT; ++r) {
        ull packed = ((ull)ford(best[r]) << 32) | (unsigned)base[r];
        atomicMax(&outmin[o0 + r * BLK], ~packed);
    }
}

// Phase 2 + finalize, one WAVE per owner: 64 lanes evaluate the winning 64-pt
// subtile with coalesced loads and the bit-identical fma chain; ballot+ffs
// picks the first exact match (numpy tie-break). Lane 0 gathers the normal and
// accumulates (1-dot)*inv. Block partials -> single accumulator in ws; the
// last block writes d_out (no d_out memset needed).
__global__ __launch_bounds__(BLK) void finalize_kernel(
    const ull* __restrict__ rowmin, const ull* __restrict__ colmin,
    const float* __restrict__ p, const float* __restrict__ g,
    const float* __restrict__ pn, const float* __restrict__ gn,
    float* __restrict__ out, float* __restrict__ accum,
    unsigned int* __restrict__ done,
    int N, int M, float invN, float invM)
{
    const int lane = threadIdx.x & 63;
    const int wid  = (blockIdx.x * BLK + threadIdx.x) >> 6;
    const int nw   = (gridDim.x * BLK) >> 6;

    float wsum = 0.0f;
    for (int o = wid; o < N + M; o += nw) {
        const float* A; const float* B; const float* An; const float* Bn;
        ull stored; int oo; float inv;
        if (o < N) { oo = o;     A = p; B = g; An = pn; Bn = gn; stored = rowmin[oo]; inv = invN; }
        else       { oo = o - N; A = g; B = p; An = gn; Bn = pn; stored = colmin[oo]; inv = invM; }
        ull packed = ~stored;
        float bestv = ford_inv((unsigned int)(packed >> 32));
        int base = (int)(packed & 0xffffffffull);

        int s = base + lane;                       // coalesced: 64 consecutive points
        float bx = B[3 * s], by = B[3 * s + 1], bz = B[3 * s + 2];
        float w = fmaf(bz, bz, fmaf(by, by, bx * bx));
        float ax = -2.0f * A[3 * oo];
        float ay = -2.0f * A[3 * oo + 1];
        float az = -2.0f * A[3 * oo + 2];
        float v = fmaf(ax, bx, fmaf(ay, by, fmaf(az, bz, w)));

        ull mask = __ballot(v == bestv);           // exact recompute: non-empty
        int bit = mask ? (__ffsll(mask) - 1) : 0;  // first (smallest s) match
        int j = base + bit;

        if (lane == 0) {
            float d = An[3 * oo] * Bn[3 * j] + An[3 * oo + 1] * Bn[3 * j + 1]
                    + An[3 * oo + 2] * Bn[3 * j + 2];
            wsum += (1.0f - d) * inv;
        }
    }

    __shared__ float part[BLK / 64];
    if (lane == 0) part[threadIdx.x >> 6] = wsum;
    __syncthreads();
    if (threadIdx.x == 0) {
        float s = 0.0f;
#pragma unroll
        for (int w = 0; w < BLK / 64; ++w) s += part[w];
        atomicAdd(accum, s);
        __threadfence();
        unsigned int c = atomicAdd(done, 1u);
        if (c == gridDim.x - 1) {
            __threadfence();
            float tot = atomicAdd(accum, 0.0f);    // atomic read of final sum
            out[0] = tot;
        }
    }
}

extern "C" void kernel_launch(void* const* d_in, const int* in_sizes, int n_in,
                              void* d_out, int out_size, void* d_ws, size_t ws_size,
                              hipStream_t stream) {
    const float* p  = (const float*)d_in[0];   // [N,3] predicted points
    const float* pn = (const float*)d_in[1];   // [N,3] predicted normals (unit)
    const float* g  = (const float*)d_in[2];   // [M,3] gt points
    const float* gn = (const float*)d_in[3];   // [M,3] gt normals (unit)
    const int N = in_sizes[0] / 3;             // 8192
    const int M = in_sizes[2] / 3;             // 32768

    ull* rowmin = (ull*)d_ws;                  // [N]   (stored complemented)
    ull* colmin = rowmin + N;                  // [M]   (stored complemented)
    float* accum = (float*)(colmin + M);       // scalar accumulator
    unsigned int* done = (unsigned int*)(accum + 1);
    float* out = (float*)d_out;

    // Single zero-memset covers mins (0 == "empty" for complemented atomicMax),
    // the float accumulator, and the done counter.
    hipMemsetAsync(d_ws, 0, (size_t)(N + M) * sizeof(ull) + 16, stream);

    const int rowSlices = M / SLICE;                 // 256
    const int colSlices = N / SLICE;                 // 64
    const int rowBlocks = (N / OWNERS) * rowSlices;  // 4*256  = 1024
    const int colBlocks = (M / OWNERS) * colSlices;  // 16*64  = 1024
    nn_min_dual<<<rowBlocks + colBlocks, BLK, 0, stream>>>(
        p, g, rowmin, colmin, rowBlocks, rowSlices, colSlices);

    finalize_kernel<<<640, BLK, 0, stream>>>(
        rowmin, colmin, p, g, pn, gn, out, accum, done, N, M, 1.0f / N, 1.0f / M);
}